// Round 2
// baseline (398.190 us; speedup 1.0000x reference)
//
#include <hip/hip_runtime.h>

#define N_VEC   131072
#define D       64
#define KCODES  1024
#define BLK     256
#define VPB     128            // vectors per block (2 threads per vector)
#define HALFK   512            // codes scanned per thread
#define KC      64             // codes per half staged per chunk (128 total in LDS)

// ws layout:
// [0, 4096)        int   counts[1024]
// [4096, 4100)     float sse
// [5120, 9216)     float esq[1024]

__device__ __forceinline__ float4 f4fma(float4 a, float4 b, float4 c) {
    return make_float4(fmaf(a.x, b.x, c.x), fmaf(a.y, b.y, c.y),
                       fmaf(a.z, b.z, c.z), fmaf(a.w, b.w, c.w));
}
__device__ __forceinline__ float f4rsum(float4 a) {
    return (a.x + a.y) + (a.z + a.w);
}

__global__ void esq_kernel(const float* __restrict__ cb, float* __restrict__ esq) {
    int k = blockIdx.x * blockDim.x + threadIdx.x;
    if (k < KCODES) {
        const float4* c4 = reinterpret_cast<const float4*>(cb + k * D);
        float4 p = make_float4(0.f, 0.f, 0.f, 0.f);
        #pragma unroll
        for (int i = 0; i < D / 4; ++i) {
            float4 v = c4[i];
            p = f4fma(v, v, p);
        }
        esq[k] = f4rsum(p);
    }
}

__launch_bounds__(BLK, 4)
__global__ void vq_main(const float* __restrict__ z_e, const float* __restrict__ cb,
                        const float* __restrict__ esq,
                        float* __restrict__ zq_out, float* __restrict__ idx_out,
                        float* __restrict__ sse, int* __restrict__ counts) {
    __shared__ float4 scb[128 * 16];     // 32 KB: 64 codes from each half
    __shared__ float  sesq[128];
    __shared__ float  sd[2][VPB];
    __shared__ int    si[2][VPB];
    __shared__ float  sred[BLK / 64];

    const int tid = threadIdx.x;
    const int vid = tid & (VPB - 1);
    const int h   = tid >> 7;            // which code-half this thread scans
    const int n   = blockIdx.x * VPB + vid;

    // load this thread's z vector into registers (threads t and t+128 duplicate; L2 absorbs)
    float4 z[16];
    const float4* z4 = reinterpret_cast<const float4*>(z_e + (size_t)n * D);
    #pragma unroll
    for (int i = 0; i < 16; ++i) z[i] = z4[i];

    float4 p = make_float4(0.f, 0.f, 0.f, 0.f);
    #pragma unroll
    for (int i = 0; i < 16; ++i) p = f4fma(z[i], z[i], p);
    const float zsq = f4rsum(p);

    float best = INFINITY;
    int   bi = 0;

    const float4* cb4 = reinterpret_cast<const float4*>(cb);

    for (int c = 0; c < HALFK / KC; ++c) {   // 8 chunks
        __syncthreads();
        // stage 64 codes from half0 (slots 0..63) and 64 from half1 (slots 64..127)
        #pragma unroll
        for (int i = 0; i < 8; ++i) {
            int m    = i * BLK + tid;        // 0..2047
            int slot = m >> 4;               // 0..127
            int e    = m & 15;
            int g    = (slot < KC) ? (c * KC + slot)
                                   : (HALFK + c * KC + (slot - KC));
            scb[m] = cb4[(size_t)g * 16 + e];
        }
        if (tid < 128) {
            int slot = tid;
            int g    = (slot < KC) ? (c * KC + slot)
                                   : (HALFK + c * KC + (slot - KC));
            sesq[slot] = esq[g];
        }
        __syncthreads();

        const int base_slot = h * KC;
        const int gbase     = h * HALFK + c * KC;
        #pragma unroll 4
        for (int kk = 0; kk < KC; ++kk) {
            float4 s = make_float4(0.f, 0.f, 0.f, 0.f);
            #pragma unroll
            for (int i = 0; i < 16; ++i)
                s = f4fma(z[i], scb[(base_slot + kk) * 16 + i], s);   // wave-uniform broadcast
            // replicate reference rounding: t1 = fp32(zsq + esq); d = fp32(t1 - 2*dot)
            float t1 = zsq + sesq[base_slot + kk];
            float d  = fmaf(-2.0f, f4rsum(s), t1);
            if (d < best) { best = d; bi = gbase + kk; }   // strict <: lowest index on tie
        }
    }

    // publish per-half results
    sd[h][vid] = best;
    si[h][vid] = bi;
    __syncthreads();

    float v = 0.f;
    if (tid < VPB) {
        float d0 = sd[0][tid], d1 = sd[1][tid];
        int   i0 = si[0][tid], i1 = si[1][tid];
        // half0 holds lower indices: on tie, half0 wins (strict <)
        float db = d0; int ib = i0;
        if (d1 < d0) { db = d1; ib = i1; }
        idx_out[n] = (float)ib;
        atomicAdd(&counts[ib], 1);
        si[0][tid] = ib;                 // for the z_q write phase
        v = db;                          // ||z - z_q||^2 == winning distance
    }
    // block sse reduction
    #pragma unroll
    for (int off = 32; off > 0; off >>= 1) v += __shfl_down(v, off);
    if ((tid & 63) == 0) sred[tid >> 6] = v;
    __syncthreads();
    if (tid == 0) atomicAdd(sse, (sred[0] + sred[1]) + (sred[2] + sred[3]));

    // coalesced z_q write: 128 vectors * 16 float4 = 2048 contiguous float4
    float4* zq4 = reinterpret_cast<float4*>(zq_out) + (size_t)blockIdx.x * (VPB * 16);
    #pragma unroll
    for (int i = 0; i < 8; ++i) {
        int m   = i * BLK + tid;         // 0..2047
        int vec = m >> 4;
        int e   = m & 15;
        int cbi = si[0][vec];
        zq4[m] = cb4[(size_t)cbi * 16 + e];
    }
}

__global__ void finalize_kernel(const int* __restrict__ counts, const float* __restrict__ sse,
                                float* __restrict__ out_loss, float* __restrict__ out_perp) {
    __shared__ float red[256];
    int tid = threadIdx.x;
    float hsum = 0.f;
    for (int k = tid; k < KCODES; k += 256) {
        float p = (float)counts[k] / (float)N_VEC;
        hsum += p * logf(p + 1e-12f);
    }
    red[tid] = hsum;
    __syncthreads();
    for (int s = 128; s > 0; s >>= 1) {
        if (tid < s) red[tid] += red[tid + s];
        __syncthreads();
    }
    if (tid == 0) {
        out_loss[0] = 1.25f * sse[0] / 8388608.0f;   // (1+BETA) * mean
        out_perp[0] = expf(-red[0]);
    }
}

extern "C" void kernel_launch(void* const* d_in, const int* in_sizes, int n_in,
                              void* d_out, int out_size, void* d_ws, size_t ws_size,
                              hipStream_t stream) {
    const float* z_e = (const float*)d_in[0];
    const float* cb  = (const float*)d_in[1];

    float* out  = (float*)d_out;
    float* zq   = out;
    float* idxo = out + (size_t)N_VEC * D;          // 8388608
    float* loss = idxo + N_VEC;                     // +131072
    float* perp = loss + 1;

    int*   counts = (int*)d_ws;
    float* sse    = (float*)((char*)d_ws + 4096);
    float* esq    = (float*)((char*)d_ws + 5120);

    hipMemsetAsync(d_ws, 0, 5120, stream);          // zero counts + sse each call
    esq_kernel<<<4, 256, 0, stream>>>(cb, esq);
    vq_main<<<N_VEC / VPB, BLK, 0, stream>>>(z_e, cb, esq, zq, idxo, sse, counts);
    finalize_kernel<<<1, 256, 0, stream>>>(counts, sse, loss, perp);
}